// Round 12
// baseline (154.365 us; speedup 1.0000x reference)
//
#include <hip/hip_runtime.h>
#include <math.h>

// ChamferDistanceL1: B=8, N=M=4096, fp32.
// R18: DIAGNOSTIC round -- buy counters for the fused kernel.
// R13/R14/R17 (three different structures) all land ~30us vs a 12-14us
// issue model; R12's one measured datapoint says the gap is STALL
// (VALUBusy 36%), but the harness's 256MiB poison-fills (~41us x5)
// permanently occupy rocprof's top-5, so the compute kernel is invisible.
// R18 = best candidate (R17 chunked butterfly + R14 occupancy: YPT=4,
// y-halves, 1024 blocks, 8 waves/SIMD, ~44 VGPR -> no R16 spill) with the
// chunk phase repeated x4 (idempotent re-min; rep-rotated chunk order
// defeats CSE; atomicMin is a side effect so no DCE). 4x13us = 52-110us
// guarantees top-5 + full counters. Decision table:
//   VALUBusy>=75%            -> issue-bound; ship REPEAT=1 (total ~66)
//   VALUBusy<50% + big FETCH -> spill; shrink regs
//   VALUBusy<50% + normal    -> latency; software-pipeline chunks
// Next round sets REPEAT=1 regardless.

#define BLK 512
#define QPB 64        // x-queries per block
#define NXT 64        // x-tiles per batch
#define YPT 4         // y-points per thread (512*4 = 2048 = one half)
#define YHALF 2048
#define NWAVE 8
#define REPEAT 4      // DIAGNOSTIC: set back to 1 after profiling

#define WSY_DWORDS (8 * NXT * 2 * YHALF)  // 2,097,152 dwords = 8 MB
#define WSX_DWORDS (8 * 2 * NXT * QPB)    // 65,536 dwords = 256 KB

__global__ void zero_out_kernel(float* __restrict__ out) { out[0] = 0.0f; }

// ---- fused kernel (N == M == 4096) ----
__global__ __launch_bounds__(BLK, 8) void chamfer_fused_kernel(
    const float* __restrict__ x, const float* __restrict__ y,
    float* __restrict__ out, unsigned* __restrict__ wsY,
    float* __restrict__ wsX) {
  __shared__ unsigned xmin[QPB];  // block x-mins (uint-ordered floats)

  const int b = blockIdx.y;
  const int xblk = blockIdx.x;
  const int half = blockIdx.z;
  const float* __restrict__ qb  = x + (size_t)b * 4096 * 3;
  const float* __restrict__ dbb = y + ((size_t)b * 4096 + half * YHALF) * 3;
  const int t = threadIdx.x;
  const int lane = t & 63;

  if (t < QPB) xmin[t] = 0x7F7FFFFFu;
  if (b == 0 && xblk == 0 && half == 0 && t == 0) out[0] = 0.0f;

  // this lane's 4 private y-points (j = r*512 + t within the half)
  float pyx[YPT], pyy[YPT], pyz[YPT], yacc[YPT];
#pragma unroll
  for (int r = 0; r < YPT; ++r) {
    const int j = r * BLK + t;
    pyx[r] = dbb[3 * j + 0];
    pyy[r] = dbb[3 * j + 1];
    pyz[r] = dbb[3 * j + 2];
    yacc[r] = 3.0e38f;
  }

  // uniform pointer to this block's 64 x-queries (scalarized loads)
  const float* __restrict__ qx0 = qb + (size_t)(xblk * QPB) * 3;

  __syncthreads();  // xmin init visible before the per-chunk ds_min below

  for (int rep = 0; rep < REPEAT; ++rep) {
    // ---- 8 chunks x 8 x-queries; inner loop pure VALU ----
    for (int c2 = 0; c2 < 8; ++c2) {
      const int c = (c2 + rep) & 7;  // rep-rotated order defeats CSE
      const float* __restrict__ qc = qx0 + 24 * c;
      float arr[8];  // per-lane chunk results (write-once, static idx)
#pragma unroll
      for (int s = 0; s < 4; ++s) {
        const float ax = qc[6 * s + 0], ay = qc[6 * s + 1],
                    az = qc[6 * s + 2];
        const float bx = qc[6 * s + 3], by = qc[6 * s + 4],
                    bz = qc[6 * s + 5];
        float da[YPT], db_[YPT];
#pragma unroll
        for (int r = 0; r < YPT; ++r) {
          da[r] =
              fabsf(ax - pyx[r]) + fabsf(ay - pyy[r]) + fabsf(az - pyz[r]);
          db_[r] =
              fabsf(bx - pyx[r]) + fabsf(by - pyy[r]) + fabsf(bz - pyz[r]);
          yacc[r] = fminf(yacc[r], fminf(da[r], db_[r]));  // v_min3_f32
        }
        arr[2 * s] = fminf(fminf(da[0], da[1]), fminf(da[2], da[3]));
        arr[2 * s + 1] = fminf(fminf(db_[0], db_[1]), fminf(db_[2], db_[3]));
      }
      // butterfly rounds 0-2: arr halves each round (verified in R17)
#pragma unroll
      for (int k = 0; k < 3; ++k) {
        const int o = 1 << k;
        const bool hi = (lane & o) != 0;
#pragma unroll
        for (int j = 0; j < (8 >> (k + 1)); ++j) {
          const float ev = arr[2 * j];
          const float ov = arr[2 * j + 1];
          const float snd = hi ? ev : ov;
          const float kp  = hi ? ov : ev;
          arr[j] = fminf(kp, __shfl_xor(snd, o, 64));
        }
      }
      // rounds 3-5: lanes sharing (lane&7) hold the same x-offset
      float m = arr[0];
      m = fminf(m, __shfl_xor(m, 8, 64));
      m = fminf(m, __shfl_xor(m, 16, 64));
      m = fminf(m, __shfl_xor(m, 32, 64));
      if (lane < 8) atomicMin(&xmin[c * 8 + lane], __float_as_uint(m));
    }
  }

  // ---- y flush: lane-private partials, coalesced, once ----
  unsigned* __restrict__ wyb =
      wsY + (((size_t)b * NXT + xblk) * 2 + half) * YHALF;
#pragma unroll
  for (int r = 0; r < YPT; ++r) {
    wyb[r * BLK + t] = __float_as_uint(yacc[r]);
  }
  __syncthreads();  // all waves' ds_min done

  if (t < QPB) {
    wsX[(((size_t)b * 2 + half) * NXT + xblk) * QPB + t] =
        __uint_as_float(xmin[t]);
  }
}

// ---- reduce: y 64-way min (+sy), x 2-way min (+sx) -> 128 atomicAdds ----
__global__ __launch_bounds__(256) void reduce_kernel(
    const unsigned* __restrict__ wsY, const float* __restrict__ wsX,
    float* __restrict__ out, float sx, float sy) {
  const int tid = blockIdx.x * 256 + threadIdx.x;  // [0, 32768)
  const int b = tid >> 12;
  const int j = tid & 4095;

  // y-side: min over the 64 x-blocks' partials for y-point (b, j)
  const int h = j >> 11;
  const int jj = j & (YHALF - 1);
  const unsigned* __restrict__ py =
      wsY + (((size_t)b * NXT) * 2 + h) * YHALF + jj;
  unsigned um = 0x7F7FFFFFu;
#pragma unroll 8
  for (int xb = 0; xb < NXT; ++xb) um = min(um, py[(size_t)xb * 2 * YHALF]);

  // x-side: min over the 2 y-halves for query (b, i=j)
  const int xt = j >> 6, q = j & 63;
  const float v0 = wsX[(((size_t)b * 2 + 0) * NXT + xt) * QPB + q];
  const float v1 = wsX[(((size_t)b * 2 + 1) * NXT + xt) * QPB + q];

  float s = __uint_as_float(um) * sy + fminf(v0, v1) * sx;
#pragma unroll
  for (int o = 32; o > 0; o >>= 1) s += __shfl_down(s, o, 64);
  __shared__ float ws[4];
  const int w = threadIdx.x >> 6;
  if ((threadIdx.x & 63) == 0) ws[w] = s;
  __syncthreads();
  if (threadIdx.x == 0) atomicAdd(out, ws[0] + ws[1] + ws[2] + ws[3]);
}

// ---------------- generic fallback (any N, M): R8 two-dir kernel ----------
#define GBLK 512
#define GQPB 64
#define GQPT 4
#define GSLICE 1024
#define GNGRP 32
#define GGRANGE (GSLICE / GNGRP)

__global__ __launch_bounds__(GBLK) void chamfer_generic_kernel(
    const float* __restrict__ x, const float* __restrict__ y,
    float* __restrict__ out, int N, int M, float sx, float sy) {
  __shared__ float4 sdb[GNGRP][GGRANGE + 1];
  __shared__ float pmin[GBLK / 64][GQPB];
  const int dir = blockIdx.z;
  const int b = blockIdx.y;
  const float* __restrict__ q  = dir ? y : x;
  const float* __restrict__ db = dir ? x : y;
  const int Nq  = dir ? M : N;
  const int Ndb = dir ? N : M;
  const float scale = dir ? sy : sx;
  const float* __restrict__ qb  = q  + (size_t)b * Nq  * 3;
  const float* __restrict__ dbb = db + (size_t)b * Ndb * 3;
  const int t = threadIdx.x;
  const int g = t >> 4, u = t & 15;
  const int q0 = blockIdx.x * GQPB;
  float qx[GQPT], qy[GQPT], qz[GQPT], dmin[GQPT];
#pragma unroll
  for (int k = 0; k < GQPT; ++k) {
    int qi = q0 + u + 16 * k;
    if (qi >= Nq) qi = Nq - 1;
    qx[k] = qb[3 * qi + 0];
    qy[k] = qb[3 * qi + 1];
    qz[k] = qb[3 * qi + 2];
    dmin[k] = 3.0e38f;
  }
  for (int s0 = 0; s0 < Ndb; s0 += GSLICE) {
    const int send = min(GSLICE, Ndb - s0);
    for (int p = t; p < send; p += GBLK) {
      const int j = s0 + p;
      sdb[p >> 5][p & 31] =
          make_float4(dbb[3 * j + 0], dbb[3 * j + 1], dbb[3 * j + 2], 0.0f);
    }
    __syncthreads();
    const int base = g * GGRANGE;
    const int lim = min(GGRANGE, max(0, send - base));
    for (int tt = 0; tt < lim; ++tt) {
      const float4 p0 = sdb[g][tt];
#pragma unroll
      for (int k = 0; k < GQPT; ++k) {
        const float d0 =
            fabsf(qx[k] - p0.x) + fabsf(qy[k] - p0.y) + fabsf(qz[k] - p0.z);
        dmin[k] = fminf(dmin[k], d0);
      }
    }
    __syncthreads();
  }
#pragma unroll
  for (int k = 0; k < GQPT; ++k) {
    float m = dmin[k];
    m = fminf(m, __shfl_xor(m, 16, 64));
    m = fminf(m, __shfl_xor(m, 32, 64));
    dmin[k] = m;
  }
  const int w = t >> 6, l = t & 63;
  if (l < 16) {
#pragma unroll
    for (int k = 0; k < GQPT; ++k) pmin[w][l + 16 * k] = dmin[k];
  }
  __syncthreads();
  if (t < GQPB) {
    float m = pmin[0][t];
#pragma unroll
    for (int ww = 1; ww < GBLK / 64; ++ww) m = fminf(m, pmin[ww][t]);
    if (q0 + t >= Nq) m = 0.0f;
#pragma unroll
    for (int o = 32; o > 0; o >>= 1) m += __shfl_down(m, o, 64);
    if (t == 0) atomicAdd(out, m * scale);
  }
}

extern "C" void kernel_launch(void* const* d_in, const int* in_sizes, int n_in,
                              void* d_out, int out_size, void* d_ws, size_t ws_size,
                              hipStream_t stream) {
  const float* x = (const float*)d_in[0];
  const float* y = (const float*)d_in[1];
  const int B = 8;
  const int N = in_sizes[0] / (B * 3);
  const int M = in_sizes[1] / (B * 3);

  float* out = (float*)d_out;
  unsigned* wsY = (unsigned*)d_ws;                 // 8 MB
  float* wsX = (float*)d_ws + WSY_DWORDS;          // + 256 KB
  const float sx = 1.0f / (float)(B * N);
  const float sy = 1.0f / (float)(B * M);

  const bool fused =
      (N == 4096 && M == 4096 &&
       ws_size >= (size_t)(WSY_DWORDS + WSX_DWORDS) * 4);
  if (fused) {
    dim3 grd(NXT, B, 2);  // 64 x-tiles * 8 batches * 2 y-halves = 1024
    chamfer_fused_kernel<<<grd, dim3(BLK), 0, stream>>>(x, y, out, wsY, wsX);
    reduce_kernel<<<(8 * 4096) / 256, 256, 0, stream>>>(wsY, wsX, out, sx, sy);
  } else {
    zero_out_kernel<<<1, 1, 0, stream>>>(out);
    const int mx = (N > M) ? N : M;
    dim3 grd((mx + GQPB - 1) / GQPB, B, 2);
    chamfer_generic_kernel<<<grd, dim3(GBLK), 0, stream>>>(
        x, y, out, N, M, sx, sy);
  }
}

// Round 13
// 86.552 us; speedup vs baseline: 1.7835x; 1.7835x over previous
//
#include <hip/hip_runtime.h>
#include <math.h>

// ChamferDistanceL1: B=8, N=M=4096, fp32.
// R19: production version of R18's diagnosed-best shape. R18 counters:
// fused@REPEAT=4 = ~27us/rep, VALUBusy 94-97% (ISSUE-BOUND), VGPR 32, no
// spill, no conflicts. Calibration: R8 and R18 both run at 2x my VALU slot
// model -> empirical floor for this structure ~22us; at 27 we're within
// ~20%. R19 = REPEAT=1, YPT=4 + y-halves (1024 blocks, 8 waves/SIMD),
// chunked register butterfly (verified R17/R18), min3-forming trees,
// out-zero merged into fused. Budget: fill ~42 (unconditional harness
// poison of d_ws, R8-proven) + fused ~27 + reduce ~3.5 + gaps ~5.
// Predict total ~76-80 (best: 81.4). If >=80.5: polish exhausted ->
// algorithmic (spatial grid) or fill-dominated floor.

#define BLK 512
#define QPB 64        // x-queries per block
#define NXT 64        // x-tiles per batch
#define YPT 4         // y-points per thread (512*4 = 2048 = one half)
#define YHALF 2048
#define NWAVE 8

#define WSY_DWORDS (8 * NXT * 2 * YHALF)  // 2,097,152 dwords = 8 MB
#define WSX_DWORDS (8 * 2 * NXT * QPB)    // 65,536 dwords = 256 KB

__global__ void zero_out_kernel(float* __restrict__ out) { out[0] = 0.0f; }

// ---- fused kernel (N == M == 4096) ----
__global__ __launch_bounds__(BLK, 8) void chamfer_fused_kernel(
    const float* __restrict__ x, const float* __restrict__ y,
    float* __restrict__ out, unsigned* __restrict__ wsY,
    float* __restrict__ wsX) {
  __shared__ unsigned xmin[QPB];  // block x-mins (uint-ordered floats)

  const int b = blockIdx.y;
  const int xblk = blockIdx.x;
  const int half = blockIdx.z;
  const float* __restrict__ qb  = x + (size_t)b * 4096 * 3;
  const float* __restrict__ dbb = y + ((size_t)b * 4096 + half * YHALF) * 3;
  const int t = threadIdx.x;
  const int lane = t & 63;

  if (t < QPB) xmin[t] = 0x7F7FFFFFu;
  if (b == 0 && xblk == 0 && half == 0 && t == 0) out[0] = 0.0f;

  // this lane's 4 private y-points (j = r*512 + t within the half)
  float pyx[YPT], pyy[YPT], pyz[YPT], yacc[YPT];
#pragma unroll
  for (int r = 0; r < YPT; ++r) {
    const int j = r * BLK + t;
    pyx[r] = dbb[3 * j + 0];
    pyy[r] = dbb[3 * j + 1];
    pyz[r] = dbb[3 * j + 2];
    yacc[r] = 3.0e38f;
  }

  // uniform pointer to this block's 64 x-queries (scalarized loads)
  const float* __restrict__ qx0 = qb + (size_t)(xblk * QPB) * 3;

  __syncthreads();  // xmin init visible before the per-chunk ds_min below

  // ---- 8 chunks x 8 x-queries; inner loop pure VALU ----
  for (int c = 0; c < 8; ++c) {
    const float* __restrict__ qc = qx0 + 24 * c;
    float arr[8];  // per-lane chunk results (write-once, static idx)
#pragma unroll
    for (int s = 0; s < 4; ++s) {
      const float ax = qc[6 * s + 0], ay = qc[6 * s + 1], az = qc[6 * s + 2];
      const float bx = qc[6 * s + 3], by = qc[6 * s + 4], bz = qc[6 * s + 5];
      float da[YPT], db_[YPT];
#pragma unroll
      for (int r = 0; r < YPT; ++r) {
        da[r]  = fabsf(ax - pyx[r]) + fabsf(ay - pyy[r]) + fabsf(az - pyz[r]);
        db_[r] = fabsf(bx - pyx[r]) + fabsf(by - pyy[r]) + fabsf(bz - pyz[r]);
        yacc[r] = fminf(yacc[r], fminf(da[r], db_[r]));  // v_min3_f32
      }
      // min3-forming nesting: v_min3 + v_min (2 instrs per tree of 4)
      arr[2 * s]     = fminf(fminf(fminf(da[0], da[1]), da[2]), da[3]);
      arr[2 * s + 1] = fminf(fminf(fminf(db_[0], db_[1]), db_[2]), db_[3]);
    }
    // butterfly rounds 0-2: arr halves each round (verified R17/R18).
    // invariant: after round k, arr[m] holds x-offset (m<<(k+1)) |
    // (lane & (2^(k+1)-1)), reduced over the lane's 2^(k+1)-XOR-group.
#pragma unroll
    for (int k = 0; k < 3; ++k) {
      const int o = 1 << k;
      const bool hi = (lane & o) != 0;
#pragma unroll
      for (int j = 0; j < (8 >> (k + 1)); ++j) {
        const float ev = arr[2 * j];      // x-offset bit_k = 0
        const float ov = arr[2 * j + 1];  // x-offset bit_k = 1
        const float snd = hi ? ev : ov;
        const float kp  = hi ? ov : ev;
        arr[j] = fminf(kp, __shfl_xor(snd, o, 64));
      }
    }
    // rounds 3-5: lanes sharing (lane&7) hold the same x-offset
    float m = arr[0];
    m = fminf(m, __shfl_xor(m, 8, 64));
    m = fminf(m, __shfl_xor(m, 16, 64));
    m = fminf(m, __shfl_xor(m, 32, 64));
    // 8 distinct addresses within the one atomic instruction; 8 waves merge
    if (lane < 8) atomicMin(&xmin[c * 8 + lane], __float_as_uint(m));
  }

  // ---- y flush: lane-private partials, coalesced, once ----
  unsigned* __restrict__ wyb =
      wsY + (((size_t)b * NXT + xblk) * 2 + half) * YHALF;
#pragma unroll
  for (int r = 0; r < YPT; ++r) {
    wyb[r * BLK + t] = __float_as_uint(yacc[r]);
  }
  __syncthreads();  // all waves' ds_min done

  if (t < QPB) {
    wsX[(((size_t)b * 2 + half) * NXT + xblk) * QPB + t] =
        __uint_as_float(xmin[t]);
  }
}

// ---- reduce: y 64-way min (+sy), x 2-way min (+sx) -> 128 atomicAdds ----
__global__ __launch_bounds__(256) void reduce_kernel(
    const unsigned* __restrict__ wsY, const float* __restrict__ wsX,
    float* __restrict__ out, float sx, float sy) {
  const int tid = blockIdx.x * 256 + threadIdx.x;  // [0, 32768)
  const int b = tid >> 12;
  const int j = tid & 4095;

  // y-side: min over the 64 x-blocks' partials for y-point (b, j)
  const int h = j >> 11;
  const int jj = j & (YHALF - 1);
  const unsigned* __restrict__ py =
      wsY + (((size_t)b * NXT) * 2 + h) * YHALF + jj;
  unsigned um = 0x7F7FFFFFu;
#pragma unroll 8
  for (int xb = 0; xb < NXT; ++xb) um = min(um, py[(size_t)xb * 2 * YHALF]);

  // x-side: min over the 2 y-halves for query (b, i=j)
  const int xt = j >> 6, q = j & 63;
  const float v0 = wsX[(((size_t)b * 2 + 0) * NXT + xt) * QPB + q];
  const float v1 = wsX[(((size_t)b * 2 + 1) * NXT + xt) * QPB + q];

  float s = __uint_as_float(um) * sy + fminf(v0, v1) * sx;
#pragma unroll
  for (int o = 32; o > 0; o >>= 1) s += __shfl_down(s, o, 64);
  __shared__ float ws[4];
  const int w = threadIdx.x >> 6;
  if ((threadIdx.x & 63) == 0) ws[w] = s;
  __syncthreads();
  if (threadIdx.x == 0) atomicAdd(out, ws[0] + ws[1] + ws[2] + ws[3]);
}

// ---------------- generic fallback (any N, M): R8 two-dir kernel ----------
#define GBLK 512
#define GQPB 64
#define GQPT 4
#define GSLICE 1024
#define GNGRP 32
#define GGRANGE (GSLICE / GNGRP)

__global__ __launch_bounds__(GBLK) void chamfer_generic_kernel(
    const float* __restrict__ x, const float* __restrict__ y,
    float* __restrict__ out, int N, int M, float sx, float sy) {
  __shared__ float4 sdb[GNGRP][GGRANGE + 1];
  __shared__ float pmin[GBLK / 64][GQPB];
  const int dir = blockIdx.z;
  const int b = blockIdx.y;
  const float* __restrict__ q  = dir ? y : x;
  const float* __restrict__ db = dir ? x : y;
  const int Nq  = dir ? M : N;
  const int Ndb = dir ? N : M;
  const float scale = dir ? sy : sx;
  const float* __restrict__ qb  = q  + (size_t)b * Nq  * 3;
  const float* __restrict__ dbb = db + (size_t)b * Ndb * 3;
  const int t = threadIdx.x;
  const int g = t >> 4, u = t & 15;
  const int q0 = blockIdx.x * GQPB;
  float qx[GQPT], qy[GQPT], qz[GQPT], dmin[GQPT];
#pragma unroll
  for (int k = 0; k < GQPT; ++k) {
    int qi = q0 + u + 16 * k;
    if (qi >= Nq) qi = Nq - 1;
    qx[k] = qb[3 * qi + 0];
    qy[k] = qb[3 * qi + 1];
    qz[k] = qb[3 * qi + 2];
    dmin[k] = 3.0e38f;
  }
  for (int s0 = 0; s0 < Ndb; s0 += GSLICE) {
    const int send = min(GSLICE, Ndb - s0);
    for (int p = t; p < send; p += GBLK) {
      const int j = s0 + p;
      sdb[p >> 5][p & 31] =
          make_float4(dbb[3 * j + 0], dbb[3 * j + 1], dbb[3 * j + 2], 0.0f);
    }
    __syncthreads();
    const int base = g * GGRANGE;
    const int lim = min(GGRANGE, max(0, send - base));
    for (int tt = 0; tt < lim; ++tt) {
      const float4 p0 = sdb[g][tt];
#pragma unroll
      for (int k = 0; k < GQPT; ++k) {
        const float d0 =
            fabsf(qx[k] - p0.x) + fabsf(qy[k] - p0.y) + fabsf(qz[k] - p0.z);
        dmin[k] = fminf(dmin[k], d0);
      }
    }
    __syncthreads();
  }
#pragma unroll
  for (int k = 0; k < GQPT; ++k) {
    float m = dmin[k];
    m = fminf(m, __shfl_xor(m, 16, 64));
    m = fminf(m, __shfl_xor(m, 32, 64));
    dmin[k] = m;
  }
  const int w = t >> 6, l = t & 63;
  if (l < 16) {
#pragma unroll
    for (int k = 0; k < GQPT; ++k) pmin[w][l + 16 * k] = dmin[k];
  }
  __syncthreads();
  if (t < GQPB) {
    float m = pmin[0][t];
#pragma unroll
    for (int ww = 1; ww < GBLK / 64; ++ww) m = fminf(m, pmin[ww][t]);
    if (q0 + t >= Nq) m = 0.0f;
#pragma unroll
    for (int o = 32; o > 0; o >>= 1) m += __shfl_down(m, o, 64);
    if (t == 0) atomicAdd(out, m * scale);
  }
}

extern "C" void kernel_launch(void* const* d_in, const int* in_sizes, int n_in,
                              void* d_out, int out_size, void* d_ws, size_t ws_size,
                              hipStream_t stream) {
  const float* x = (const float*)d_in[0];
  const float* y = (const float*)d_in[1];
  const int B = 8;
  const int N = in_sizes[0] / (B * 3);
  const int M = in_sizes[1] / (B * 3);

  float* out = (float*)d_out;
  unsigned* wsY = (unsigned*)d_ws;                 // 8 MB
  float* wsX = (float*)d_ws + WSY_DWORDS;          // + 256 KB
  const float sx = 1.0f / (float)(B * N);
  const float sy = 1.0f / (float)(B * M);

  const bool fused =
      (N == 4096 && M == 4096 &&
       ws_size >= (size_t)(WSY_DWORDS + WSX_DWORDS) * 4);
  if (fused) {
    dim3 grd(NXT, B, 2);  // 64 x-tiles * 8 batches * 2 y-halves = 1024
    chamfer_fused_kernel<<<grd, dim3(BLK), 0, stream>>>(x, y, out, wsY, wsX);
    reduce_kernel<<<(8 * 4096) / 256, 256, 0, stream>>>(wsY, wsX, out, sx, sy);
  } else {
    zero_out_kernel<<<1, 1, 0, stream>>>(out);
    const int mx = (N > M) ? N : M;
    dim3 grd((mx + GQPB - 1) / GQPB, B, 2);
    chamfer_generic_kernel<<<grd, dim3(GBLK), 0, stream>>>(
        x, y, out, N, M, sx, sy);
  }
}